// Round 5
// baseline (254.699 us; speedup 1.0000x reference)
//
#include <hip/hip_runtime.h>
#include <hip/hip_bf16.h>
#include <string.h>

// ConvEmbedding: out[b,t,c] = bias[c] + sum_k W[c, x[b,t+k-4], k]
// B=8, T=4096, H=512, V=32000, K=9.
//
// R5: R4 fused pipeline (transpose chunk i+1 || gather chunk i) plus:
//  - nontemporal loads for the W stream, nontemporal stores for out
//    (only Wt competes for Infinity Cache -> producer->consumer stays cached)
//  - transpose blocks cover 7 full vocab rows (63m x 128c): each touched slot
//    written as one contiguous 2304B segment (wave-wide uint2, 512B/inst)
//  - XOR-swizzled LDS tile: conflict-free float4 reads on the pack side

#define Hc 512
#define Vc 32000
#define Kc 9
#define Tc 4096
#define Bc 8
#define Mc (Vc * Kc)              // 288000
#define VT 7                      // vocab rows per transpose tile
#define NMT 4572                  // ceil(V / VT)
#define NM_TILE (VT * Kc)         // 63
#define CHUNK_C 128
#define NCHUNK 4
#define ROW_U (Kc * CHUNK_C / 2)  // 576 uints = 2304 B per slot row per chunk
#define WT_ROWS (Vc + 1)
#define T_TILE 32
#define NGB 1024                  // gather blocks per chunk (8 b x 128 t-tiles)
#define GRID_N 5715               // 1143 groups of 5 (4 transpose + 1 gather)

__device__ __forceinline__ unsigned int f2bf(float f) {
  unsigned int u = __float_as_uint(f);
  u += 0x7FFFu + ((u >> 16) & 1u);  // round-to-nearest-even
  return u >> 16;
}

// Assign compact slots (1..) to touched vocab ids; slot[] pre-set -1. Slot 0
// is the zero row (sequence-boundary padding).
__global__ __launch_bounds__(256) void mark_kernel(
    const int* __restrict__ x, int* __restrict__ slot, int* __restrict__ counter) {
  const int i = blockIdx.x * 256 + threadIdx.x;  // B*T = 32768
  const int v = x[i];
  if (atomicCAS(&slot[v], -1, -2147483647) == -1) {
    slot[v] = 1 + atomicAdd(counter, 1);
  }
}

// Fused: blockIdx.x grouped in 5s -> 4 transpose roles + 1 gather role.
__global__ __launch_bounds__(256) void fused_kernel(
    const float* __restrict__ W, const int* __restrict__ x,
    const int* __restrict__ slot, const float* __restrict__ bias,
    float* __restrict__ out, unsigned int* __restrict__ wbuf,
    const unsigned int* __restrict__ rbuf, int tchunk, int gchunk) {
  __shared__ float tile[NM_TILE * CHUNK_C];  // 63*128 f32 = 32.25 KB
  const int bx = blockIdx.x;
  const int grp = bx / 5;
  const int rem = bx % 5;
  const int tid = threadIdx.x;

  if (rem == 4) {
    // ---------------- gather role ----------------
    if (gchunk < 0 || grp >= NGB) return;
    int* ids = (int*)tile;  // 40 entries
    const int b = grp >> 7;
    const int t0 = (grp & 127) * T_TILE;
    if (tid < T_TILE + Kc - 1) {
      const int s = t0 + tid - (Kc / 2);
      ids[tid] = (s >= 0 && s < Tc) ? slot[x[b * Tc + s]] : 0;
    }
    __syncthreads();
    const int lane = tid & 63;
    const int w = tid >> 6;  // wave handles tt = w*8 .. w*8+7
    const int c0 = gchunk * CHUNK_C;
    const int cpl = 2 * lane;  // channel pair within chunk
    const float2 b2 = *(const float2*)(bias + c0 + cpl);
#pragma unroll
    for (int i = 0; i < 8; ++i) {
      const int tt = w * 8 + i;
      float2 acc = b2;
#pragma unroll
      for (int k = 0; k < Kc; ++k) {
        const int id = ids[tt + k];
        const unsigned int wv =
            rbuf[(size_t)id * ROW_U + k * (CHUNK_C / 2) + lane];
        acc.x += __uint_as_float(wv << 16);
        acc.y += __uint_as_float(wv & 0xFFFF0000u);
      }
      double d;
      memcpy(&d, &acc, 8);
      __builtin_nontemporal_store(
          d, (double*)(out + ((size_t)(b * Tc + t0 + tt) << 9) + c0 + cpl));
    }
    return;
  }

  // ---------------- transpose role ----------------
  if (tchunk >= NCHUNK) return;
  const int tb = grp * 4 + rem;  // 0..4571
  if (tb >= NMT) return;
  const int v0 = tb * VT;
  const int nv = (Vc - v0 < VT) ? (Vc - v0) : VT;
  const int nm = nv * Kc;
  const int m0 = v0 * Kc;
  const int cbase = tchunk * CHUNK_C;
  const int tx = tid & 63;   // m index
  const int ty = tid >> 6;   // c group 0..3
  if (tx < nm) {
    const float* wp = W + (size_t)(cbase + ty * 32) * Mc + m0 + tx;
#pragma unroll
    for (int r = 0; r < 32; ++r) {
      const int c = ty * 32 + r;
      const float val = __builtin_nontemporal_load(wp + (size_t)r * Mc);
      tile[tx * CHUNK_C + (c ^ ((tx & 7) << 2))] = val;
    }
  }
  __syncthreads();
  uint2* wbuf2 = (uint2*)wbuf;
  for (int vl = 0; vl < nv; ++vl) {
    const int s = slot[v0 + vl];
    if (s < 0) continue;  // untouched vocab: never read, skip
    for (int j = tid; j < 288; j += 256) {
      const int k = j >> 5;  // 0..8
      const int q = j & 31;  // c-quad index
      const int m = vl * Kc + k;
      const float4 f =
          *(const float4*)&tile[m * CHUNK_C + ((4 * q) ^ ((m & 7) << 2))];
      uint2 val;
      val.x = f2bf(f.x) | (f2bf(f.y) << 16);
      val.y = f2bf(f.z) | (f2bf(f.w) << 16);
      wbuf2[(size_t)s * 288 + j] = val;  // 2304B contiguous per slot
    }
  }
}

// Fallback (ws too small): direct, slow but correct.
__global__ __launch_bounds__(256) void conv_fallback_kernel(
    const int* __restrict__ x, const float* __restrict__ W,
    const float* __restrict__ bias, float* __restrict__ out) {
  const size_t idx = (size_t)blockIdx.x * 256 + threadIdx.x;
  const int c = (int)(idx & (Hc - 1));
  const size_t bt = idx >> 9;
  const int t = (int)(bt & (Tc - 1));
  const int b = (int)(bt >> 12);
  float acc = bias[c];
#pragma unroll
  for (int k = 0; k < Kc; ++k) {
    const int s = t + k - (Kc / 2);
    if (s >= 0 && s < Tc) {
      const int id = x[b * Tc + s];
      acc += W[(size_t)c * Mc + (size_t)id * Kc + k];
    }
  }
  out[idx] = acc;
}

extern "C" void kernel_launch(void* const* d_in, const int* in_sizes, int n_in,
                              void* d_out, int out_size, void* d_ws, size_t ws_size,
                              hipStream_t stream) {
  const int* x = (const int*)d_in[0];
  const float* W = (const float*)d_in[1];
  const float* bias = (const float*)d_in[2];
  float* out = (float*)d_out;

  // ws layout: buf0, buf1 (worst-case WT_ROWS rows each), slot[V], counter
  const size_t buf_bytes = (size_t)WT_ROWS * ROW_U * 4;  // 73,730,304 B
  const size_t buf1_off = buf_bytes;
  const size_t slot_off = 2 * buf_bytes;
  const size_t cnt_off = slot_off + (size_t)Vc * 4;
  const size_t need = cnt_off + 4;

  if (ws_size >= need) {
    unsigned int* buf0 = (unsigned int*)d_ws;
    unsigned int* buf1 = (unsigned int*)((char*)d_ws + buf1_off);
    int* slot = (int*)((char*)d_ws + slot_off);
    int* counter = (int*)((char*)d_ws + cnt_off);
    hipMemsetAsync(slot, 0xFF, (size_t)Vc * 4, stream);
    hipMemsetAsync(counter, 0, 4, stream);
    hipMemsetAsync(buf0, 0, ROW_U * 4, stream);  // zero row (slot 0)
    hipMemsetAsync(buf1, 0, ROW_U * 4, stream);
    mark_kernel<<<(Bc * Tc) / 256, 256, 0, stream>>>(x, slot, counter);
    for (int l = 0; l <= NCHUNK; ++l) {
      const int tchunk = l;      // NCHUNK means "no transpose this launch"
      const int gchunk = l - 1;  // -1 means "no gather this launch"
      unsigned int* wbuf = (tchunk & 1) ? buf1 : buf0;
      const unsigned int* rbuf = (gchunk >= 0 && (gchunk & 1)) ? buf1 : buf0;
      fused_kernel<<<GRID_N, 256, 0, stream>>>(W, x, slot, bias, out, wbuf,
                                               rbuf, tchunk, gchunk);
    }
  } else {
    const size_t n = (size_t)Bc * Tc * Hc;
    conv_fallback_kernel<<<(int)(n / 256), 256, 0, stream>>>(x, W, bias, out);
  }
}

// Round 6
// 241.011 us; speedup vs baseline: 1.0568x; 1.0568x over previous
//
#include <hip/hip_runtime.h>
#include <hip/hip_bf16.h>

// ConvEmbedding: out[b,t,c] = bias[c] + sum_k W[c, x[b,t+k-4], k]
// B=8, T=4096, H=512, V=32000, K=9.
//
// R6: SERIAL chunk phases, SINGLE Wt buffer (the anti-R4):
//   mark -> T0 G0 T1 G1 T2 G2 T3 G3.
// Per-chunk working set (148 MB W stream + 47 MB Wt + 17 MB out) < 256 MB
// Infinity Cache, so gather i reads Wt from L3 (no HBM re-read), and
// transpose i+1 re-dirties the SAME buffer while resident (no HBM writeback
// of version i). Expected HBM ~= 590 (W) + 67 (out) + <=47 residual.

#define Hc 512
#define Vc 32000
#define Kc 9
#define Tc 4096
#define Bc 8
#define Mc (Vc * Kc)              // 288000
#define CHUNK_C 128
#define NCHUNK 4
#define ROW_U (Kc * CHUNK_C / 2)  // 576 uints = 2304 B per slot row per chunk
#define WT_ROWS (Vc + 1)          // all-distinct worst case + zero row
#define T_TILE 32

__device__ __forceinline__ unsigned int f2bf(float f) {
  unsigned int u = __float_as_uint(f);
  u += 0x7FFFu + ((u >> 16) & 1u);  // round-to-nearest-even
  return u >> 16;
}

// Assign compact slots (1..) to touched vocab ids; slot[] pre-set -1. Slot 0
// is the zero row (sequence-boundary padding).
__global__ __launch_bounds__(256) void mark_kernel(
    const int* __restrict__ x, int* __restrict__ slot, int* __restrict__ counter) {
  const int i = blockIdx.x * 256 + threadIdx.x;  // B*T = 32768
  const int v = x[i];
  if (atomicCAS(&slot[v], -1, -2147483647) == -1) {
    slot[v] = 1 + atomicAdd(counter, 1);
  }
}

// Transpose one 128-c chunk of W into compact Wt. grid = (4500, 2).
__global__ __launch_bounds__(256) void transpose_chunk_kernel(
    const float* __restrict__ W, const int* __restrict__ slot,
    unsigned int* __restrict__ wbuf, int chunk) {
  __shared__ float tile[64][65];
  const int m0 = blockIdx.x * 64;
  const int ct = blockIdx.y;                       // 64-c half within chunk
  const int cbase = chunk * CHUNK_C + ct * 64;
  const int tid = threadIdx.x;
  const int tx = tid & 63;
  const int ty = tid >> 6;  // 0..3
#pragma unroll
  for (int r = 0; r < 16; ++r) {
    const int row = ty * 16 + r;  // c_local 0..63
    tile[row][tx] = W[(size_t)(cbase + row) * Mc + (m0 + tx)];
  }
  __syncthreads();
  const int u = tid & 31;   // c-pair index within the 64-c half
  const int rl = tid >> 5;  // 0..7
#pragma unroll
  for (int p = 0; p < 8; ++p) {
    const int mrow = p * 8 + rl;  // 0..63
    const int m = m0 + mrow;
    const int v = m / Kc;
    const int k = m - v * Kc;
    const int s = slot[v];
    if (s >= 0) {
      const unsigned int val = f2bf(tile[2 * u][mrow]) |
                               (f2bf(tile[2 * u + 1][mrow]) << 16);
      wbuf[(size_t)s * ROW_U + k * (CHUNK_C / 2) + ct * 32 + u] = val;
    }
  }
}

// Gather one 128-c chunk. grid = 1024 (8 b x 128 t-tiles).
__global__ __launch_bounds__(256) void gather_chunk_kernel(
    const int* __restrict__ x, const int* __restrict__ slot,
    const unsigned int* __restrict__ rbuf, const float* __restrict__ bias,
    float* __restrict__ out, int chunk) {
  __shared__ int ids[T_TILE + Kc - 1];  // 40 compact slot ids
  const int gb = blockIdx.x;
  const int b = gb >> 7;
  const int t0 = (gb & 127) * T_TILE;
  const int tid = threadIdx.x;
  if (tid < T_TILE + Kc - 1) {
    const int s = t0 + tid - (Kc / 2);
    ids[tid] = (s >= 0 && s < Tc) ? slot[x[b * Tc + s]] : 0;
  }
  __syncthreads();
  const int lane = tid & 63;
  const int w = tid >> 6;  // wave handles tt = w*8 .. w*8+7
  const int c0 = chunk * CHUNK_C;
  const int cpl = 2 * lane;  // channel pair within chunk
  const float2 b2 = *(const float2*)(bias + c0 + cpl);
#pragma unroll
  for (int i = 0; i < 8; ++i) {
    const int tt = w * 8 + i;
    float2 acc = b2;
#pragma unroll
    for (int k = 0; k < Kc; ++k) {
      const int id = ids[tt + k];
      const unsigned int wv =
          rbuf[(size_t)id * ROW_U + k * (CHUNK_C / 2) + lane];
      acc.x += __uint_as_float(wv << 16);
      acc.y += __uint_as_float(wv & 0xFFFF0000u);
    }
    *(float2*)(out + ((size_t)(b * Tc + t0 + tt) << 9) + c0 + cpl) = acc;
  }
}

// Fallback (ws too small): direct, slow but correct.
__global__ __launch_bounds__(256) void conv_fallback_kernel(
    const int* __restrict__ x, const float* __restrict__ W,
    const float* __restrict__ bias, float* __restrict__ out) {
  const size_t idx = (size_t)blockIdx.x * 256 + threadIdx.x;
  const int c = (int)(idx & (Hc - 1));
  const size_t bt = idx >> 9;
  const int t = (int)(bt & (Tc - 1));
  const int b = (int)(bt >> 12);
  float acc = bias[c];
#pragma unroll
  for (int k = 0; k < Kc; ++k) {
    const int s = t + k - (Kc / 2);
    if (s >= 0 && s < Tc) {
      const int id = x[b * Tc + s];
      acc += W[(size_t)c * Mc + (size_t)id * Kc + k];
    }
  }
  out[idx] = acc;
}

extern "C" void kernel_launch(void* const* d_in, const int* in_sizes, int n_in,
                              void* d_out, int out_size, void* d_ws, size_t ws_size,
                              hipStream_t stream) {
  const int* x = (const int*)d_in[0];
  const float* W = (const float*)d_in[1];
  const float* bias = (const float*)d_in[2];
  float* out = (float*)d_out;

  // ws layout: one Wt chunk buffer (worst-case rows), slot[V], counter
  const size_t buf_bytes = (size_t)WT_ROWS * ROW_U * 4;  // 73,730,304 B
  const size_t slot_off = buf_bytes;
  const size_t cnt_off = slot_off + (size_t)Vc * 4;
  const size_t need = cnt_off + 4;

  if (ws_size >= need) {
    unsigned int* buf = (unsigned int*)d_ws;
    int* slot = (int*)((char*)d_ws + slot_off);
    int* counter = (int*)((char*)d_ws + cnt_off);
    hipMemsetAsync(slot, 0xFF, (size_t)Vc * 4, stream);
    hipMemsetAsync(counter, 0, 4, stream);
    hipMemsetAsync(buf, 0, ROW_U * 4, stream);  // zero row (slot 0)
    mark_kernel<<<(Bc * Tc) / 256, 256, 0, stream>>>(x, slot, counter);
    dim3 tg(4500, 2);
    for (int chunk = 0; chunk < NCHUNK; ++chunk) {
      transpose_chunk_kernel<<<tg, 256, 0, stream>>>(W, slot, buf, chunk);
      gather_chunk_kernel<<<1024, 256, 0, stream>>>(x, slot, buf, bias, out,
                                                    chunk);
    }
  } else {
    const size_t n = (size_t)Bc * Tc * Hc;
    conv_fallback_kernel<<<(int)(n / 256), 256, 0, stream>>>(x, W, bias, out);
  }
}